// Round 6
// baseline (2274.653 us; speedup 1.0000x reference)
//
#include <hip/hip_runtime.h>
#include <math.h>

#define N_TOK 8192
#define DIM   768
#define MEMN  10000
#define MEMP  10240            // padded to 40*256
#define TQ    32
#define TM    256
#define NSPLIT 2
#define TILES_PER_SPLIT 20
#define NBLK  512              // attn grid size (pacing target)

constexpr float SCALE = 0.036084391824351615f;  // 1/sqrt(768)

typedef short bf16x8 __attribute__((ext_vector_type(8)));
typedef float f32x4  __attribute__((ext_vector_type(4)));

__device__ __forceinline__ unsigned short f2bf(float f) {
    unsigned u = __float_as_uint(f);
    unsigned r = (u + 0x7fffu + ((u >> 16) & 1u)) >> 16;   // RTN-even
    return (unsigned short)r;
}

// ---------------------------------------------------------------------------
// mem fp32 [10000][768] -> memH bf16 [10240][768], padded rows zero.
// ---------------------------------------------------------------------------
__global__ void cvt_memH(const float* __restrict__ mem, unsigned short* __restrict__ dst)
{
    const int m = blockIdx.x;
    const int d = threadIdx.x * 4;
    float4 v = make_float4(0.f, 0.f, 0.f, 0.f);
    if (m < MEMN) v = *(const float4*)&mem[(size_t)m * DIM + d];
    ushort4 o;
    o.x = f2bf(v.x); o.y = f2bf(v.y); o.z = f2bf(v.z); o.w = f2bf(v.w);
    *(ushort4*)&dst[(size_t)m * DIM + d] = o;
}

// ---------------------------------------------------------------------------
// Q fp32 [8192][768] -> qH bf16 (row-major, same layout)
// ---------------------------------------------------------------------------
__global__ void cvt_qH(const float* __restrict__ q, unsigned short* __restrict__ dst)
{
    const size_t i = ((size_t)blockIdx.x * 256 + threadIdx.x) * 4;
    float4 v = *(const float4*)&q[i];
    ushort4 o;
    o.x = f2bf(v.x); o.y = f2bf(v.y); o.z = f2bf(v.z); o.w = f2bf(v.w);
    *(ushort4*)&dst[i] = o;
}

// ---------------------------------------------------------------------------
// memT bf16 [768][10240]: memT[d][m] = mem[m][d] (0 for m>=10000)
// ---------------------------------------------------------------------------
__global__ void transpose_mem(const float* __restrict__ mem, unsigned short* __restrict__ memT)
{
    __shared__ float T[32][33];
    const int mb = blockIdx.x * 32, db = blockIdx.y * 32;
    const int tx = threadIdx.x & 31, ty = threadIdx.x >> 5;   // ty 0..7
#pragma unroll
    for (int i = 0; i < 4; ++i) {
        int m = mb + ty + 8 * i;
        T[ty + 8 * i][tx] = (m < MEMN) ? mem[(size_t)m * DIM + db + tx] : 0.f;
    }
    __syncthreads();
#pragma unroll
    for (int i = 0; i < 4; ++i) {
        int d = ty + 8 * i;
        memT[(size_t)(db + d) * MEMP + mb + tx] = f2bf(T[tx][d]);
    }
}

// ---------------------------------------------------------------------------
// Fused MFMA attention, 2-way m-split, 512-thread blocks (8 waves).
// Round-6: soft PACING barrier per m-tile (bounded spin on a global counter)
// keeps all 512 blocks within ~1 tile of each other -> per-XCD L2 window
// ~1.6-3 MB < 4 MB, so mem tiles are filled once per XCD instead of ~9x.
// Correctness NEVER depends on the barrier (spin is capped); graph-safe.
// ---------------------------------------------------------------------------
__global__ __launch_bounds__(512, 4)
void attn_mfma(const unsigned short* __restrict__ qH, const unsigned short* __restrict__ memH,
               const unsigned short* __restrict__ memT,
               float* __restrict__ retrRaw, float* __restrict__ Lvec,
               unsigned* __restrict__ pace)
{
    __shared__ __align__(16) unsigned short Qs[32 * 768];   // 48 KB, xor-swizzled
    __shared__ __align__(16) unsigned short Ps[32 * 256];   // 16 KB, xor-swizzled

    const int tid    = threadIdx.x;
    const int w      = tid >> 6;         // wave 0..7
    const int lane   = tid & 63;
    const int quad   = lane >> 4;        // 0..3
    const int l16    = lane & 15;

    // ---- XCD-aware (qi, split) swizzle (kept; harmless) ----
    const int lb    = blockIdx.x + gridDim.x * blockIdx.y;   // 0..511
    const int split = (lb >> 2) & 1;
    const int qi    = ((lb >> 3) << 2) | (lb & 3);           // 0..255
    const int q0    = qi * TQ;

    const int dbase  = w * 96;           // phase-2 d-strip per wave
    const int mstrip = w * 32;           // phase-1 m-strip per wave

    // ---- stage Q tile (bf16, swizzled) once ----
    {
        const int qr  = tid >> 4;            // 0..31
        const int db0 = tid & 15;
        const unsigned short* src = qH + (size_t)(q0 + qr) * DIM;
        const int sw = qr & 7;
#pragma unroll
        for (int i = 0; i < 6; ++i) {
            int db = db0 + i * 16;           // 0..95 (blocks of 8 bf16)
            uint4 v = *(const uint4*)&src[db * 8];
            *(uint4*)&Qs[qr * 768 + ((db ^ sw) << 3)] = v;
        }
    }
    __syncthreads();

    f32x4 oacc[2][6];
#pragma unroll
    for (int a = 0; a < 2; ++a)
#pragma unroll
        for (int b = 0; b < 6; ++b) oacc[a][b] = (f32x4){0.f, 0.f, 0.f, 0.f};
    float lsum[2][4] = {{0.f, 0.f, 0.f, 0.f}, {0.f, 0.f, 0.f, 0.f}};

    const int xsw = l16 & 7;

    for (int st = 0; st < TILES_PER_SPLIT; ++st) {
        const int m0 = (split * TILES_PER_SPLIT + st) * TM;

        // ---- phase 1: S[32 x 256]; wave w covers m-strip mstrip..+32 ----
        f32x4 sacc[2][2];
#pragma unroll
        for (int a = 0; a < 2; ++a)
#pragma unroll
            for (int b = 0; b < 2; ++b) sacc[a][b] = (f32x4){0.f, 0.f, 0.f, 0.f};

        const unsigned short* brow = memH + (size_t)(m0 + mstrip + l16) * DIM + quad * 8;

        bf16x8 b0 = *(const bf16x8*)(brow);
        bf16x8 b1 = *(const bf16x8*)(brow + 16 * DIM);
        {
            const int xq0 = ((quad) ^ xsw) << 3;
            bf16x8 a0 = *(const bf16x8*)&Qs[l16 * 768 + xq0];
            bf16x8 a1 = *(const bf16x8*)&Qs[(16 + l16) * 768 + xq0];
            for (int kc = 0; kc < DIM - 32; kc += 32) {
                const int nk = kc + 32;
                // prefetch next iteration's fragments
                bf16x8 nb0 = *(const bf16x8*)(brow + nk);
                bf16x8 nb1 = *(const bf16x8*)(brow + 16 * DIM + nk);
                const int xq = (((nk >> 3) + quad) ^ xsw) << 3;
                bf16x8 na0 = *(const bf16x8*)&Qs[l16 * 768 + xq];
                bf16x8 na1 = *(const bf16x8*)&Qs[(16 + l16) * 768 + xq];
                sacc[0][0] = __builtin_amdgcn_mfma_f32_16x16x32_bf16(a0, b0, sacc[0][0], 0, 0, 0);
                sacc[1][0] = __builtin_amdgcn_mfma_f32_16x16x32_bf16(a1, b0, sacc[1][0], 0, 0, 0);
                sacc[0][1] = __builtin_amdgcn_mfma_f32_16x16x32_bf16(a0, b1, sacc[0][1], 0, 0, 0);
                sacc[1][1] = __builtin_amdgcn_mfma_f32_16x16x32_bf16(a1, b1, sacc[1][1], 0, 0, 0);
                a0 = na0; a1 = na1; b0 = nb0; b1 = nb1;
            }
            // peeled last iteration (no wrap prefetch)
            sacc[0][0] = __builtin_amdgcn_mfma_f32_16x16x32_bf16(a0, b0, sacc[0][0], 0, 0, 0);
            sacc[1][0] = __builtin_amdgcn_mfma_f32_16x16x32_bf16(a1, b0, sacc[1][0], 0, 0, 0);
            sacc[0][1] = __builtin_amdgcn_mfma_f32_16x16x32_bf16(a0, b1, sacc[0][1], 0, 0, 0);
            sacc[1][1] = __builtin_amdgcn_mfma_f32_16x16x32_bf16(a1, b1, sacc[1][1], 0, 0, 0);
        }

        __syncthreads();   // barrier A: all waves done reading previous tile's Ps

        // ---- exp + P->LDS (bf16, swizzled) + row-sum accumulation ----
#pragma unroll
        for (int qt = 0; qt < 2; ++qt)
#pragma unroll
            for (int mt = 0; mt < 2; ++mt) {
                const int mloc = mstrip + mt * 16 + l16;      // 0..255
                const bool ok  = (m0 + mloc) < MEMN;
#pragma unroll
                for (int r = 0; r < 4; ++r) {
                    float p = ok ? __expf(sacc[qt][mt][r] * SCALE) : 0.f;
                    const int q = qt * 16 + quad * 4 + r;
                    lsum[qt][r] += p;
                    Ps[q * 256 + (((mloc >> 3) ^ (q & 7)) << 3) + (mloc & 7)] = f2bf(p);
                }
            }

        __syncthreads();   // barrier B: Ps complete

        // ---- phase 2: O += P * Mem; wave w covers d-strip dbase..+96 ----
        const unsigned short* mtp = memT + (size_t)(dbase + l16) * MEMP + m0 + quad * 8;
        bf16x8 c[6];
#pragma unroll
        for (int nt = 0; nt < 6; ++nt)
            c[nt] = *(const bf16x8*)(mtp + (size_t)nt * 16 * MEMP);

        {
            const int xp0 = ((quad) ^ xsw) << 3;
            bf16x8 pa0 = *(const bf16x8*)&Ps[l16 * 256 + xp0];
            bf16x8 pa1 = *(const bf16x8*)&Ps[(16 + l16) * 256 + xp0];
            for (int kc = 0; kc < TM - 32; kc += 32) {
                const int nk = kc + 32;
                const int xp = (((nk >> 3) + quad) ^ xsw) << 3;
                bf16x8 npa0 = *(const bf16x8*)&Ps[l16 * 256 + xp];
                bf16x8 npa1 = *(const bf16x8*)&Ps[(16 + l16) * 256 + xp];
#pragma unroll
                for (int nt = 0; nt < 6; ++nt) {
                    oacc[0][nt] = __builtin_amdgcn_mfma_f32_16x16x32_bf16(pa0, c[nt], oacc[0][nt], 0, 0, 0);
                    oacc[1][nt] = __builtin_amdgcn_mfma_f32_16x16x32_bf16(pa1, c[nt], oacc[1][nt], 0, 0, 0);
                    // reload this slot for the next kc right after its last use
                    c[nt] = *(const bf16x8*)(mtp + (size_t)nt * 16 * MEMP + nk);
                }
                pa0 = npa0; pa1 = npa1;
            }
            // peeled last iteration (no wrap reload)
#pragma unroll
            for (int nt = 0; nt < 6; ++nt) {
                oacc[0][nt] = __builtin_amdgcn_mfma_f32_16x16x32_bf16(pa0, c[nt], oacc[0][nt], 0, 0, 0);
                oacc[1][nt] = __builtin_amdgcn_mfma_f32_16x16x32_bf16(pa1, c[nt], oacc[1][nt], 0, 0, 0);
            }
        }

        // ---- soft pacing barrier (performance-only; capped spin => no hang) ----
        if (st + 1 < TILES_PER_SPLIT) {
            if (tid == 0) {
                __hip_atomic_fetch_add(pace, 1u, __ATOMIC_RELEASE, __HIP_MEMORY_SCOPE_AGENT);
                const unsigned target = (unsigned)(st + 1) * NBLK;
                int spins = 0;
                while (__hip_atomic_load(pace, __ATOMIC_ACQUIRE, __HIP_MEMORY_SCOPE_AGENT) < target
                       && spins < (1 << 15)) {
                    ++spins;
                    __builtin_amdgcn_s_sleep(2);
                }
            }
            __syncthreads();
        }
    }

    // ---- epilogue: atomically combine O and L across splits ----
#pragma unroll
    for (int qt = 0; qt < 2; ++qt)
#pragma unroll
        for (int nt = 0; nt < 6; ++nt)
#pragma unroll
            for (int r = 0; r < 4; ++r)
                __hip_atomic_fetch_add(
                    &retrRaw[(size_t)(q0 + qt * 16 + quad * 4 + r) * DIM + dbase + nt * 16 + l16],
                    oacc[qt][nt][r], __ATOMIC_RELAXED, __HIP_MEMORY_SCOPE_AGENT);

#pragma unroll
    for (int qt = 0; qt < 2; ++qt)
#pragma unroll
        for (int r = 0; r < 4; ++r) {
            float v = lsum[qt][r];
#pragma unroll
            for (int off = 1; off < 16; off <<= 1) v += __shfl_xor(v, off);
            if (l16 == 0)
                __hip_atomic_fetch_add(&Lvec[q0 + qt * 16 + quad * 4 + r], v,
                                       __ATOMIC_RELAXED, __HIP_MEMORY_SCOPE_AGENT);
        }
}

// ---------------------------------------------------------------------------
// Normalize retrieved in place + gate. One wave per row.
// ---------------------------------------------------------------------------
__global__ __launch_bounds__(256)
void finalize_gate(float* __restrict__ retr, const float* __restrict__ Lvec,
                   const float* __restrict__ cs, const float* __restrict__ gw,
                   const float* __restrict__ gb, float* __restrict__ gvec)
{
    const int lane = threadIdx.x & 63;
    const int row  = blockIdx.x * 4 + (threadIdx.x >> 6);
    const float rl = 1.0f / Lvec[row];
    float* rr = retr + (size_t)row * DIM;
    const float* cr = cs + (size_t)row * DIM;
    float g = 0.f;
#pragma unroll
    for (int i = 0; i < 12; ++i) {
        int c = lane + 64 * i;
        float r = rr[c] * rl;
        rr[c] = r;
        g += cr[c] * gw[c] + r * gw[DIM + c];
    }
#pragma unroll
    for (int off = 32; off > 0; off >>= 1) g += __shfl_xor(g, off);
    g += gb[0];
    g = 1.0f / (1.0f + __expf(-g));
    if (lane == 0) gvec[row] = g;
}

// ---------------------------------------------------------------------------
__global__ void prep_w1s(const float* __restrict__ w1, float* __restrict__ w1s)
{
    int i = (blockIdx.x * 256 + threadIdx.x) * 4;
    float4 a = *(const float4*)&w1[i];
    float4 b = *(const float4*)&w1[589824 + i];
    *(float4*)&w1s[i] = make_float4(a.x + b.x, a.y + b.y, a.z + b.z, a.w + b.w);
}

// ---------------------------------------------------------------------------
// MLP GEMM (fp32 VALU), tile = 16 rows x 768 cols, 256 threads.
// MODE 0: h = gelu(x@W1s + r@W1c + b1), x = cs + g*r built during staging.
// MODE 1: out = LayerNorm(h@W2 + b2)*gamma + beta (LN fused, wave owns rows).
// ---------------------------------------------------------------------------
template <int MODE>
__global__ __launch_bounds__(256, 2)
void mlp_kernel(const float* __restrict__ A1, const float* __restrict__ W1,
                const float* __restrict__ A2, const float* __restrict__ W2,
                const float* __restrict__ bias, const float* __restrict__ gvec,
                const float* __restrict__ gamma, const float* __restrict__ beta,
                float* __restrict__ out)
{
    __shared__ __align__(16) float As[16][20];
    __shared__ __align__(16) float Ws[16][DIM + 8];

    const int tid = threadIdx.x;
    const int r0  = blockIdx.x * 16;
    const int tq  = tid >> 6;
    const int td  = tid & 63;

    float acc[4][12];
#pragma unroll
    for (int a = 0; a < 4; ++a)
#pragma unroll
        for (int b = 0; b < 12; ++b) acc[a][b] = 0.f;

    const int nsrc = (MODE == 0) ? 2 : 1;
    for (int src = 0; src < nsrc; ++src) {
        const float* A = src ? A2 : A1;
        const float* W = src ? W2 : W1;
        for (int kc = 0; kc < DIM; kc += 16) {
            __syncthreads();
            if (tid < 64) {
                int row = tid >> 2, k4 = (tid & 3) * 4;
                float4 v = *(const float4*)&A[(size_t)(r0 + row) * DIM + kc + k4];
                if (MODE == 0 && src == 0) {
                    float g = gvec[r0 + row];
                    float4 r = *(const float4*)&A2[(size_t)(r0 + row) * DIM + kc + k4];
                    v.x += g * r.x; v.y += g * r.y; v.z += g * r.z; v.w += g * r.w;
                }
                As[k4 + 0][row] = v.x;
                As[k4 + 1][row] = v.y;
                As[k4 + 2][row] = v.z;
                As[k4 + 3][row] = v.w;
            }
#pragma unroll
            for (int i = 0; i < 12; ++i) {
                int f  = tid + i * 256;
                int kr = f / 192;
                int c4 = (f - kr * 192) * 4;
                float4 v = *(const float4*)&W[(size_t)(kc + kr) * DIM + c4];
                *(float4*)&Ws[kr][c4] = v;
            }
            __syncthreads();
#pragma unroll
            for (int k = 0; k < 16; ++k) {
                float4 av = *(const float4*)&As[k][tq * 4];
                float4 w0 = *(const float4*)&Ws[k][td * 12];
                float4 w1 = *(const float4*)&Ws[k][td * 12 + 4];
                float4 w2 = *(const float4*)&Ws[k][td * 12 + 8];
                float aa[4]  = {av.x, av.y, av.z, av.w};
                float ww[12] = {w0.x, w0.y, w0.z, w0.w, w1.x, w1.y, w1.z, w1.w,
                                w2.x, w2.y, w2.z, w2.w};
#pragma unroll
                for (int a = 0; a < 4; ++a)
#pragma unroll
                    for (int b = 0; b < 12; ++b)
                        acc[a][b] += aa[a] * ww[b];
            }
        }
    }

    float4 t0 = *(const float4*)&bias[td * 12];
    float4 t1 = *(const float4*)&bias[td * 12 + 4];
    float4 t2 = *(const float4*)&bias[td * 12 + 8];
    float bv[12] = {t0.x, t0.y, t0.z, t0.w, t1.x, t1.y, t1.z, t1.w, t2.x, t2.y, t2.z, t2.w};

    if (MODE == 0) {
#pragma unroll
        for (int a = 0; a < 4; ++a) {
            int row = r0 + tq * 4 + a;
            float vv[12];
#pragma unroll
            for (int b = 0; b < 12; ++b) {
                float v = acc[a][b] + bv[b];
                vv[b] = 0.5f * v * (1.0f + erff(v * 0.7071067811865476f));
            }
            float* ob = out + (size_t)row * DIM + td * 12;
            *(float4*)(ob)     = make_float4(vv[0], vv[1], vv[2],  vv[3]);
            *(float4*)(ob + 4) = make_float4(vv[4], vv[5], vv[6],  vv[7]);
            *(float4*)(ob + 8) = make_float4(vv[8], vv[9], vv[10], vv[11]);
        }
    } else {
        float4 g0 = *(const float4*)&gamma[td * 12];
        float4 g1 = *(const float4*)&gamma[td * 12 + 4];
        float4 g2 = *(const float4*)&gamma[td * 12 + 8];
        float4 e0 = *(const float4*)&beta[td * 12];
        float4 e1 = *(const float4*)&beta[td * 12 + 4];
        float4 e2 = *(const float4*)&beta[td * 12 + 8];
        float gv[12] = {g0.x, g0.y, g0.z, g0.w, g1.x, g1.y, g1.z, g1.w, g2.x, g2.y, g2.z, g2.w};
        float ev[12] = {e0.x, e0.y, e0.z, e0.w, e1.x, e1.y, e1.z, e1.w, e2.x, e2.y, e2.z, e2.w};
#pragma unroll
        for (int a = 0; a < 4; ++a) {
            float v[12];
            float s1 = 0.f, s2 = 0.f;
#pragma unroll
            for (int b = 0; b < 12; ++b) {
                v[b] = acc[a][b] + bv[b];
                s1 += v[b];
                s2 += v[b] * v[b];
            }
#pragma unroll
            for (int off = 32; off > 0; off >>= 1) {
                s1 += __shfl_xor(s1, off);
                s2 += __shfl_xor(s2, off);
            }
            float mu  = s1 * (1.0f / 768.0f);
            float var = fmaxf(s2 * (1.0f / 768.0f) - mu * mu, 0.f);
            float rs  = rsqrtf(var + 1e-5f);
            int row = r0 + tq * 4 + a;
            float ov[12];
#pragma unroll
            for (int b = 0; b < 12; ++b)
                ov[b] = (v[b] - mu) * rs * gv[b] + ev[b];
            float* ob = out + (size_t)row * DIM + td * 12;
            *(float4*)(ob)     = make_float4(ov[0], ov[1], ov[2],  ov[3]);
            *(float4*)(ob + 4) = make_float4(ov[4], ov[5], ov[6],  ov[7]);
            *(float4*)(ob + 8) = make_float4(ov[8], ov[9], ov[10], ov[11]);
        }
    }
}

// ---------------------------------------------------------------------------
extern "C" void kernel_launch(void* const* d_in, const int* in_sizes, int n_in,
                              void* d_out, int out_size, void* d_ws, size_t ws_size,
                              hipStream_t stream)
{
    const float* cs  = (const float*)d_in[0];
    const float* mem = (const float*)d_in[1];
    const float* gw  = (const float*)d_in[2];
    const float* gb  = (const float*)d_in[3];
    const float* fw1 = (const float*)d_in[4];
    const float* fb1 = (const float*)d_in[5];
    const float* fw2 = (const float*)d_in[6];
    const float* fb2 = (const float*)d_in[7];
    const float* gam = (const float*)d_in[8];
    const float* bet = (const float*)d_in[9];
    float* out = (float*)d_out;

    char* ws = (char*)d_ws;
    // layout (bytes), total ~71.6 MB (round-1's 78 MB ran clean):
    unsigned short* memH = (unsigned short*)ws;                 // 15,728,640
    unsigned short* memT = (unsigned short*)(ws + 15728640);    // 15,728,640
    unsigned short* qH   = (unsigned short*)(ws + 31457280);    // 12,582,912
    float*    retr = (float*)(ws + 44040192);                   // 25,165,824
    float*    Lvec = (float*)(ws + 69206016);                   // 32,768
    unsigned* pace = (unsigned*)(ws + 69238784);                // 64 (pad)
    float*    gvec = (float*)(ws + 69238848);                   // 32,768
    float*    w1s  = (float*)(ws + 69271616);                   // 2,359,296 -> end 71,630,912
    float*    hbuf = (float*)ws;   // alias memH/memT/qH (dead after attn), 25.2 MB

    // zero-init atomic accumulation buffers + pacing counter (contiguous)
    hipMemsetAsync(retr, 0, (size_t)N_TOK * DIM * 4 + 32768 + 64, stream);

    cvt_memH<<<MEMP, 192, 0, stream>>>(mem, memH);
    cvt_qH<<<(N_TOK * DIM) / (256 * 4), 256, 0, stream>>>(cs, qH);
    transpose_mem<<<dim3(MEMP / 32, DIM / 32), 256, 0, stream>>>(mem, memT);
    prep_w1s<<<576, 256, 0, stream>>>(fw1, w1s);

    attn_mfma<<<dim3(N_TOK / TQ, NSPLIT), 512, 0, stream>>>(qH, memH, memT, retr, Lvec, pace);
    finalize_gate<<<N_TOK / 4, 256, 0, stream>>>(retr, Lvec, cs, gw, gb, gvec);
    mlp_kernel<0><<<N_TOK / 16, 256, 0, stream>>>(cs, w1s, retr, fw1 + 2 * 589824, fb1,
                                                  gvec, nullptr, nullptr, hbuf);
    mlp_kernel<1><<<N_TOK / 16, 256, 0, stream>>>(hbuf, fw2, nullptr, nullptr, fb2,
                                                  nullptr, gam, bet, out);
}

// Round 7
// 1282.438 us; speedup vs baseline: 1.7737x; 1.7737x over previous
//
#include <hip/hip_runtime.h>
#include <math.h>

#define N_TOK 8192
#define DIM   768
#define MEMN  10000
#define MEMP  10240            // padded to 40*256
#define TQ    32
#define TM    256
#define NSPLIT 2
#define TILES_PER_SPLIT 20

constexpr float SCALE = 0.036084391824351615f;  // 1/sqrt(768)

typedef short bf16x8 __attribute__((ext_vector_type(8)));
typedef float f32x4  __attribute__((ext_vector_type(4)));

__device__ __forceinline__ unsigned short f2bf(float f) {
    unsigned u = __float_as_uint(f);
    unsigned r = (u + 0x7fffu + ((u >> 16) & 1u)) >> 16;   // RTN-even
    return (unsigned short)r;
}

// ---------------------------------------------------------------------------
// mem fp32 [10000][768] -> memH bf16 [10240][768], padded rows zero.
// ---------------------------------------------------------------------------
__global__ void cvt_memH(const float* __restrict__ mem, unsigned short* __restrict__ dst)
{
    const int m = blockIdx.x;
    const int d = threadIdx.x * 4;
    float4 v = make_float4(0.f, 0.f, 0.f, 0.f);
    if (m < MEMN) v = *(const float4*)&mem[(size_t)m * DIM + d];
    ushort4 o;
    o.x = f2bf(v.x); o.y = f2bf(v.y); o.z = f2bf(v.z); o.w = f2bf(v.w);
    *(ushort4*)&dst[(size_t)m * DIM + d] = o;
}

// ---------------------------------------------------------------------------
// Q fp32 -> bf16 (row-major, same layout)
// ---------------------------------------------------------------------------
__global__ void cvt_qH(const float* __restrict__ q, unsigned short* __restrict__ dst)
{
    const size_t i = ((size_t)blockIdx.x * 256 + threadIdx.x) * 4;
    float4 v = *(const float4*)&q[i];
    ushort4 o;
    o.x = f2bf(v.x); o.y = f2bf(v.y); o.z = f2bf(v.z); o.w = f2bf(v.w);
    *(ushort4*)&dst[i] = o;
}

// ---------------------------------------------------------------------------
// memT bf16 [768][10240]: memT[d][m] = mem[m][d] (0 for m>=10000)
// ---------------------------------------------------------------------------
__global__ void transpose_mem(const float* __restrict__ mem, unsigned short* __restrict__ memT)
{
    __shared__ float T[32][33];
    const int mb = blockIdx.x * 32, db = blockIdx.y * 32;
    const int tx = threadIdx.x & 31, ty = threadIdx.x >> 5;   // ty 0..7
#pragma unroll
    for (int i = 0; i < 4; ++i) {
        int m = mb + ty + 8 * i;
        T[ty + 8 * i][tx] = (m < MEMN) ? mem[(size_t)m * DIM + db + tx] : 0.f;
    }
    __syncthreads();
#pragma unroll
    for (int i = 0; i < 4; ++i) {
        int d = ty + 8 * i;
        memT[(size_t)(db + d) * MEMP + mb + tx] = f2bf(T[tx][d]);
    }
}

// ---------------------------------------------------------------------------
// W12T bf16 [768 n][1536 k]: k<768 -> w1[k][n]+w1[768+k][n]; else w1[768+k][n]
// grid (1536/32, 768/32), 256 thr
// ---------------------------------------------------------------------------
__global__ void prep_w12T(const float* __restrict__ w1, unsigned short* __restrict__ wt)
{
    __shared__ float T[32][33];
    const int kb = blockIdx.x * 32, nb = blockIdx.y * 32;
    const int tx = threadIdx.x & 31, ty = threadIdx.x >> 5;
#pragma unroll
    for (int i = 0; i < 4; ++i) {
        int k = kb + ty + 8 * i;
        float v = w1[(size_t)(768 + k) * DIM + nb + tx];
        if (kb < 768) v += w1[(size_t)k * DIM + nb + tx];
        T[ty + 8 * i][tx] = v;
    }
    __syncthreads();
#pragma unroll
    for (int i = 0; i < 4; ++i) {
        int n = nb + ty + 8 * i;
        wt[(size_t)n * 1536 + kb + tx] = f2bf(T[tx][ty + 8 * i]);
    }
}

// ---------------------------------------------------------------------------
// W2T bf16 [768 n][768 k] = w2[k][n]. grid (24,24), 256 thr
// ---------------------------------------------------------------------------
__global__ void prep_w2T(const float* __restrict__ w2, unsigned short* __restrict__ wt)
{
    __shared__ float T[32][33];
    const int kb = blockIdx.x * 32, nb = blockIdx.y * 32;
    const int tx = threadIdx.x & 31, ty = threadIdx.x >> 5;
#pragma unroll
    for (int i = 0; i < 4; ++i)
        T[ty + 8 * i][tx] = w2[(size_t)(kb + ty + 8 * i) * DIM + nb + tx];
    __syncthreads();
#pragma unroll
    for (int i = 0; i < 4; ++i)
        wt[(size_t)(nb + ty + 8 * i) * DIM + kb + tx] = f2bf(T[tx][ty + 8 * i]);
}

// ---------------------------------------------------------------------------
// Fused MFMA attention (round-5 structure, no pacing), 512-thr blocks.
// Round-7: phase-2 B-fragments double-buffered in registers (depth-2 global
// prefetch, cb[2][6]) to tolerate ~2x more L2/L3 miss latency.
// ---------------------------------------------------------------------------
__global__ __launch_bounds__(512, 4)
void attn_mfma(const unsigned short* __restrict__ qH, const unsigned short* __restrict__ memH,
               const unsigned short* __restrict__ memT,
               float* __restrict__ retrRaw, float* __restrict__ Lvec)
{
    __shared__ __align__(16) unsigned short Qs[32 * 768];   // 48 KB, xor-swizzled
    __shared__ __align__(16) unsigned short Ps[32 * 256];   // 16 KB, xor-swizzled

    const int tid    = threadIdx.x;
    const int w      = tid >> 6;         // wave 0..7
    const int lane   = tid & 63;
    const int quad   = lane >> 4;        // 0..3
    const int l16    = lane & 15;

    const int lb    = blockIdx.x + gridDim.x * blockIdx.y;   // 0..511
    const int split = (lb >> 2) & 1;
    const int qi    = ((lb >> 3) << 2) | (lb & 3);           // 0..255
    const int q0    = qi * TQ;

    const int dbase  = w * 96;           // phase-2 d-strip per wave
    const int mstrip = w * 32;           // phase-1 m-strip per wave

    // ---- stage Q tile (bf16, swizzled) once ----
    {
        const int qr  = tid >> 4;            // 0..31
        const int db0 = tid & 15;
        const unsigned short* src = qH + (size_t)(q0 + qr) * DIM;
        const int sw = qr & 7;
#pragma unroll
        for (int i = 0; i < 6; ++i) {
            int db = db0 + i * 16;           // 0..95 (blocks of 8 bf16)
            uint4 v = *(const uint4*)&src[db * 8];
            *(uint4*)&Qs[qr * 768 + ((db ^ sw) << 3)] = v;
        }
    }
    __syncthreads();

    f32x4 oacc[2][6];
#pragma unroll
    for (int a = 0; a < 2; ++a)
#pragma unroll
        for (int b = 0; b < 6; ++b) oacc[a][b] = (f32x4){0.f, 0.f, 0.f, 0.f};
    float lsum[2][4] = {{0.f, 0.f, 0.f, 0.f}, {0.f, 0.f, 0.f, 0.f}};

    const int xsw = l16 & 7;

    for (int st = 0; st < TILES_PER_SPLIT; ++st) {
        const int m0 = (split * TILES_PER_SPLIT + st) * TM;

        // ---- phase 1: S[32 x 256]; wave w covers m-strip mstrip..+32 ----
        f32x4 sacc[2][2];
#pragma unroll
        for (int a = 0; a < 2; ++a)
#pragma unroll
            for (int b = 0; b < 2; ++b) sacc[a][b] = (f32x4){0.f, 0.f, 0.f, 0.f};

        const unsigned short* brow = memH + (size_t)(m0 + mstrip + l16) * DIM + quad * 8;

        bf16x8 b0 = *(const bf16x8*)(brow);
        bf16x8 b1 = *(const bf16x8*)(brow + 16 * DIM);
        {
            const int xq0 = ((quad) ^ xsw) << 3;
            bf16x8 a0 = *(const bf16x8*)&Qs[l16 * 768 + xq0];
            bf16x8 a1 = *(const bf16x8*)&Qs[(16 + l16) * 768 + xq0];
            for (int kc = 0; kc < DIM - 32; kc += 32) {
                const int nk = kc + 32;
                bf16x8 nb0 = *(const bf16x8*)(brow + nk);
                bf16x8 nb1 = *(const bf16x8*)(brow + 16 * DIM + nk);
                const int xq = (((nk >> 3) + quad) ^ xsw) << 3;
                bf16x8 na0 = *(const bf16x8*)&Qs[l16 * 768 + xq];
                bf16x8 na1 = *(const bf16x8*)&Qs[(16 + l16) * 768 + xq];
                sacc[0][0] = __builtin_amdgcn_mfma_f32_16x16x32_bf16(a0, b0, sacc[0][0], 0, 0, 0);
                sacc[1][0] = __builtin_amdgcn_mfma_f32_16x16x32_bf16(a1, b0, sacc[1][0], 0, 0, 0);
                sacc[0][1] = __builtin_amdgcn_mfma_f32_16x16x32_bf16(a0, b1, sacc[0][1], 0, 0, 0);
                sacc[1][1] = __builtin_amdgcn_mfma_f32_16x16x32_bf16(a1, b1, sacc[1][1], 0, 0, 0);
                a0 = na0; a1 = na1; b0 = nb0; b1 = nb1;
            }
            sacc[0][0] = __builtin_amdgcn_mfma_f32_16x16x32_bf16(a0, b0, sacc[0][0], 0, 0, 0);
            sacc[1][0] = __builtin_amdgcn_mfma_f32_16x16x32_bf16(a1, b0, sacc[1][0], 0, 0, 0);
            sacc[0][1] = __builtin_amdgcn_mfma_f32_16x16x32_bf16(a0, b1, sacc[0][1], 0, 0, 0);
            sacc[1][1] = __builtin_amdgcn_mfma_f32_16x16x32_bf16(a1, b1, sacc[1][1], 0, 0, 0);
        }

        __syncthreads();   // barrier A: all waves done reading previous tile's Ps

        // ---- exp + P->LDS (bf16, swizzled) + row-sum accumulation ----
#pragma unroll
        for (int qt = 0; qt < 2; ++qt)
#pragma unroll
            for (int mt = 0; mt < 2; ++mt) {
                const int mloc = mstrip + mt * 16 + l16;      // 0..255
                const bool ok  = (m0 + mloc) < MEMN;
#pragma unroll
                for (int r = 0; r < 4; ++r) {
                    float p = ok ? __expf(sacc[qt][mt][r] * SCALE) : 0.f;
                    const int q = qt * 16 + quad * 4 + r;
                    lsum[qt][r] += p;
                    Ps[q * 256 + (((mloc >> 3) ^ (q & 7)) << 3) + (mloc & 7)] = f2bf(p);
                }
            }

        __syncthreads();   // barrier B: Ps complete

        // ---- phase 2: O += P * Mem; depth-2 register prefetch of B-frags ----
        const unsigned short* mtp = memT + (size_t)(dbase + l16) * MEMP + m0 + quad * 8;
        bf16x8 cb[2][6];
#pragma unroll
        for (int nt = 0; nt < 6; ++nt) {
            cb[0][nt] = *(const bf16x8*)(mtp + (size_t)nt * 16 * MEMP);
            cb[1][nt] = *(const bf16x8*)(mtp + (size_t)nt * 16 * MEMP + 32);
        }

        {
            const int xp0 = ((quad) ^ xsw) << 3;
            bf16x8 pa0 = *(const bf16x8*)&Ps[l16 * 256 + xp0];
            bf16x8 pa1 = *(const bf16x8*)&Ps[(16 + l16) * 256 + xp0];
#pragma unroll
            for (int ks = 0; ks < 8; ++ks) {
                const int kc  = ks * 32;
                const int nkp = (ks < 7) ? kc + 32 : 0;
                const int xp = (((nkp >> 3) + quad) ^ xsw) << 3;
                bf16x8 npa0 = *(const bf16x8*)&Ps[l16 * 256 + xp];
                bf16x8 npa1 = *(const bf16x8*)&Ps[(16 + l16) * 256 + xp];
                const int pf = kc + 64;               // prefetch 2 steps ahead
                const bool dopf = (ks < 6);
#pragma unroll
                for (int nt = 0; nt < 6; ++nt) {
                    oacc[0][nt] = __builtin_amdgcn_mfma_f32_16x16x32_bf16(pa0, cb[ks & 1][nt], oacc[0][nt], 0, 0, 0);
                    oacc[1][nt] = __builtin_amdgcn_mfma_f32_16x16x32_bf16(pa1, cb[ks & 1][nt], oacc[1][nt], 0, 0, 0);
                    if (dopf) cb[ks & 1][nt] = *(const bf16x8*)(mtp + (size_t)nt * 16 * MEMP + pf);
                }
                pa0 = npa0; pa1 = npa1;
            }
        }
    }

    // ---- epilogue: atomically combine O and L across splits ----
#pragma unroll
    for (int qt = 0; qt < 2; ++qt)
#pragma unroll
        for (int nt = 0; nt < 6; ++nt)
#pragma unroll
            for (int r = 0; r < 4; ++r)
                __hip_atomic_fetch_add(
                    &retrRaw[(size_t)(q0 + qt * 16 + quad * 4 + r) * DIM + dbase + nt * 16 + l16],
                    oacc[qt][nt][r], __ATOMIC_RELAXED, __HIP_MEMORY_SCOPE_AGENT);

#pragma unroll
    for (int qt = 0; qt < 2; ++qt)
#pragma unroll
        for (int r = 0; r < 4; ++r) {
            float v = lsum[qt][r];
#pragma unroll
            for (int off = 1; off < 16; off <<= 1) v += __shfl_xor(v, off);
            if (l16 == 0)
                __hip_atomic_fetch_add(&Lvec[q0 + qt * 16 + quad * 4 + r], v,
                                       __ATOMIC_RELAXED, __HIP_MEMORY_SCOPE_AGENT);
        }
}

// ---------------------------------------------------------------------------
// Normalize retrieved, compute gate, build XRb = bf16([cs + g*r | r]).
// One wave per row (4 rows / 256-thr block). gvec eliminated.
// ---------------------------------------------------------------------------
__global__ __launch_bounds__(256)
void finalize_xr(const float* __restrict__ retrRaw, const float* __restrict__ Lvec,
                 const float* __restrict__ cs, const float* __restrict__ gw,
                 const float* __restrict__ gb, unsigned short* __restrict__ XRb)
{
    const int lane = threadIdx.x & 63;
    const int row  = blockIdx.x * 4 + (threadIdx.x >> 6);
    const float rl = 1.0f / Lvec[row];
    const float* rr = retrRaw + (size_t)row * DIM;
    const float* cr = cs + (size_t)row * DIM;

    float4 rv[3], cv[3];
    float d = 0.f;
#pragma unroll
    for (int i = 0; i < 3; ++i) {
        const int c4 = i * 256 + lane * 4;
        float4 r = *(const float4*)&rr[c4];
        r.x *= rl; r.y *= rl; r.z *= rl; r.w *= rl;
        float4 c = *(const float4*)&cr[c4];
        float4 g1 = *(const float4*)&gw[c4];
        float4 g2 = *(const float4*)&gw[DIM + c4];
        d += c.x * g1.x + c.y * g1.y + c.z * g1.z + c.w * g1.w;
        d += r.x * g2.x + r.y * g2.y + r.z * g2.z + r.w * g2.w;
        rv[i] = r; cv[i] = c;
    }
#pragma unroll
    for (int off = 32; off > 0; off >>= 1) d += __shfl_xor(d, off);
    d += gb[0];
    const float g = 1.0f / (1.0f + __expf(-d));

    unsigned short* xb = XRb + (size_t)row * 1536;
#pragma unroll
    for (int i = 0; i < 3; ++i) {
        const int c4 = i * 256 + lane * 4;
        ushort4 xo, ro;
        xo.x = f2bf(cv[i].x + g * rv[i].x); xo.y = f2bf(cv[i].y + g * rv[i].y);
        xo.z = f2bf(cv[i].z + g * rv[i].z); xo.w = f2bf(cv[i].w + g * rv[i].w);
        ro.x = f2bf(rv[i].x); ro.y = f2bf(rv[i].y);
        ro.z = f2bf(rv[i].z); ro.w = f2bf(rv[i].w);
        *(ushort4*)&xb[c4] = xo;
        *(ushort4*)&xb[DIM + c4] = ro;
    }
}

// ---------------------------------------------------------------------------
// MFMA GEMM: C[M x 768] = A[M x K](bf16) @ WT[768 x K](bf16, [n][k]) + bias.
// Block 256 thr (4 waves), 16 rows; wave owns 192 n-cols. K-chunks of 256
// staged in swizzled LDS; B-frags from global (L2-resident W), depth-1 reload.
// ACT 0: gelu -> bf16 out.  ACT 1: LayerNorm*gamma+beta -> fp32 out.
// ---------------------------------------------------------------------------
template <int K, int ACT>
__global__ __launch_bounds__(256, 2)
void gemm_mfma(const unsigned short* __restrict__ A, const unsigned short* __restrict__ WT,
               const float* __restrict__ bias, const float* __restrict__ gamma,
               const float* __restrict__ beta, void* __restrict__ outv)
{
    __shared__ __align__(16) unsigned short As[16 * 256];   // 8 KB, xor-swizzled
    __shared__ float red[2][4][16];

    const int tid  = threadIdx.x;
    const int w    = tid >> 6;
    const int lane = tid & 63;
    const int quad = lane >> 4;
    const int l16  = lane & 15;
    const int row0 = blockIdx.x * 16;
    const int nbase = w * 192;
    const int xsw3 = l16 & 7;

    f32x4 acc[12];
#pragma unroll
    for (int nt = 0; nt < 12; ++nt) acc[nt] = (f32x4){0.f, 0.f, 0.f, 0.f};

    bf16x8 b[12];
#pragma unroll
    for (int nt = 0; nt < 12; ++nt)
        b[nt] = *(const bf16x8*)&WT[(size_t)(nbase + nt * 16 + l16) * K + quad * 8];

    for (int ch = 0; ch < K / 256; ++ch) {
        const int kc0 = ch * 256;
        __syncthreads();
#pragma unroll
        for (int i = 0; i < 2; ++i) {
            const int f = tid + i * 256;
            const int r = f >> 5, kb8 = f & 31;
            *(uint4*)&As[r * 256 + ((kb8 ^ (r & 7)) << 3)] =
                *(const uint4*)&A[(size_t)(row0 + r) * K + kc0 + kb8 * 8];
        }
        __syncthreads();
#pragma unroll
        for (int ks = 0; ks < 8; ++ks) {
            const int kc = ks * 32;
            bf16x8 af = *(const bf16x8*)&As[l16 * 256 + ((((kc >> 3) + quad) ^ xsw3) << 3)];
            int gn = kc0 + kc + 32;
            if (gn >= K) gn = 0;                      // dummy wrap (harmless)
#pragma unroll
            for (int nt = 0; nt < 12; ++nt) {
                acc[nt] = __builtin_amdgcn_mfma_f32_16x16x32_bf16(af, b[nt], acc[nt], 0, 0, 0);
                b[nt] = *(const bf16x8*)&WT[(size_t)(nbase + nt * 16 + l16) * K + gn + quad * 8];
            }
        }
    }

    float bv[12];
#pragma unroll
    for (int nt = 0; nt < 12; ++nt) bv[nt] = bias[nbase + nt * 16 + l16];

    if (ACT == 0) {
        unsigned short* out = (unsigned short*)outv;
#pragma unroll
        for (int nt = 0; nt < 12; ++nt)
#pragma unroll
            for (int r = 0; r < 4; ++r) {
                const int row = row0 + quad * 4 + r;
                float v = acc[nt][r] + bv[nt];
                v = 0.5f * v * (1.0f + erff(v * 0.7071067811865476f));
                out[(size_t)row * DIM + nbase + nt * 16 + l16] = f2bf(v);
            }
    } else {
        float* out = (float*)outv;
        float v[12][4];
        float s1[4] = {0.f, 0.f, 0.f, 0.f}, s2[4] = {0.f, 0.f, 0.f, 0.f};
#pragma unroll
        for (int nt = 0; nt < 12; ++nt)
#pragma unroll
            for (int r = 0; r < 4; ++r) {
                float t = acc[nt][r] + bv[nt];
                v[nt][r] = t;
                s1[r] += t;
                s2[r] += t * t;
            }
#pragma unroll
        for (int r = 0; r < 4; ++r) {
#pragma unroll
            for (int off = 1; off < 16; off <<= 1) {
                s1[r] += __shfl_xor(s1[r], off);
                s2[r] += __shfl_xor(s2[r], off);
            }
            if (l16 == 0) {
                red[0][w][quad * 4 + r] = s1[r];
                red[1][w][quad * 4 + r] = s2[r];
            }
        }
        __syncthreads();
#pragma unroll
        for (int r = 0; r < 4; ++r) {
            const int rl16 = quad * 4 + r;
            const float t1 = red[0][0][rl16] + red[0][1][rl16] + red[0][2][rl16] + red[0][3][rl16];
            const float t2 = red[1][0][rl16] + red[1][1][rl16] + red[1][2][rl16] + red[1][3][rl16];
            const float mu  = t1 * (1.0f / 768.0f);
            const float var = fmaxf(t2 * (1.0f / 768.0f) - mu * mu, 0.f);
            const float rs  = rsqrtf(var + 1e-5f);
            const int row = row0 + rl16;
#pragma unroll
            for (int nt = 0; nt < 12; ++nt) {
                const int col = nbase + nt * 16 + l16;
                out[(size_t)row * DIM + col] = (v[nt][r] - mu) * rs * gamma[col] + beta[col];
            }
        }
    }
}

// ---------------------------------------------------------------------------
extern "C" void kernel_launch(void* const* d_in, const int* in_sizes, int n_in,
                              void* d_out, int out_size, void* d_ws, size_t ws_size,
                              hipStream_t stream)
{
    const float* cs  = (const float*)d_in[0];
    const float* mem = (const float*)d_in[1];
    const float* gw  = (const float*)d_in[2];
    const float* gb  = (const float*)d_in[3];
    const float* fw1 = (const float*)d_in[4];
    const float* fb1 = (const float*)d_in[5];
    const float* fw2 = (const float*)d_in[6];
    const float* fb2 = (const float*)d_in[7];
    const float* gam = (const float*)d_in[8];
    const float* bet = (const float*)d_in[9];
    float* out = (float*)d_out;

    char* ws = (char*)d_ws;
    // layout (bytes), total ~72.8 MB (78 MB proven safe in round 1):
    unsigned short* memH = (unsigned short*)ws;                 // 15,728,640
    unsigned short* memT = (unsigned short*)(ws + 15728640);    // 15,728,640
    unsigned short* qH   = (unsigned short*)(ws + 31457280);    // 12,582,912
    float*          retr = (float*)(ws + 44040192);             // 25,165,824 (raw partials)
    float*          Lvec = (float*)(ws + 69206016);             // 32,768
    unsigned short* w12T = (unsigned short*)(ws + 69238784);    // 2,359,296
    unsigned short* w2T  = (unsigned short*)(ws + 71598080);    // 1,179,648 -> end 72,777,728
    unsigned short* XRb  = (unsigned short*)ws;                 // alias memH+memT (dead after attn)
    unsigned short* hb   = qH;                                  // alias qH (dead after attn)

    // zero-init atomic accumulation buffers (retr + Lvec contiguous)
    hipMemsetAsync(retr, 0, 25165824 + 32768, stream);

    cvt_memH<<<MEMP, 192, 0, stream>>>(mem, memH);
    cvt_qH<<<(N_TOK * DIM) / (256 * 4), 256, 0, stream>>>(cs, qH);
    transpose_mem<<<dim3(MEMP / 32, DIM / 32), 256, 0, stream>>>(mem, memT);
    prep_w12T<<<dim3(48, 24), 256, 0, stream>>>(fw1, w12T);
    prep_w2T<<<dim3(24, 24), 256, 0, stream>>>(fw2, w2T);

    attn_mfma<<<dim3(N_TOK / TQ, NSPLIT), 512, 0, stream>>>(qH, memH, memT, retr, Lvec);
    finalize_xr<<<N_TOK / 4, 256, 0, stream>>>(retr, Lvec, cs, gw, gb, XRb);
    gemm_mfma<1536, 0><<<N_TOK / 16, 256, 0, stream>>>(XRb, w12T, fb1, nullptr, nullptr, hb);
    gemm_mfma<768, 1><<<N_TOK / 16, 256, 0, stream>>>(hb, w2T, fb2, gam, bet, out);
}